// Round 1
// baseline (273.030 us; speedup 1.0000x reference)
//
#include <hip/hip_runtime.h>
#include <math.h>

// Problem dims (fixed by setup_inputs)
namespace {
constexpr int Bn = 4, Cn = 128, Tn = 32, Hn = 24, Wn = 24, Mn = 3;
constexpr int HWn = Hn * Wn;      // 576
constexpr int TTile = 8;          // time tile per conv block
constexpr int PL = TTile + 2;     // input planes per tile (causal halo 2)
constexpr int RSf = 32;           // LDS row stride in floats (bank-aligned, 8 chunks)
constexpr int PRows = 26;         // rows per plane: h = -1..24 stored at rs = 0..25
constexpr int PSf = PRows * RSf;  // 832 floats per plane
}

// ---------------- Kernel A: spatial mean pool q -> qg[B*C*T] ----------------
// 4 planes per 256-thread block (1 wave per plane), float4 loads.
__global__ __launch_bounds__(256) void pool_kernel(const float* __restrict__ q,
                                                   float* __restrict__ qg) {
    int wave = threadIdx.x >> 6;
    int lane = threadIdx.x & 63;
    int plane = blockIdx.x * 4 + wave;
    const float4* p = (const float4*)(q + (size_t)plane * HWn);  // 144 float4
    float4 a = p[lane];
    float4 b = p[lane + 64];
    float s = (a.x + a.y) + (a.z + a.w) + (b.x + b.y) + (b.z + b.w);
    if (lane < 16) {
        float4 c = p[128 + lane];
        s += (c.x + c.y) + (c.z + c.w);
    }
#pragma unroll
    for (int off = 32; off > 0; off >>= 1) s += __shfl_down(s, off);
    if (lane == 0) qg[plane] = s * (1.0f / 576.0f);
}

// ---------------- Kernel B: alpha[B*M*T] from qg ----------------
__global__ __launch_bounds__(512) void alpha_kernel(const float* __restrict__ qg,
                                                    const float* __restrict__ pre_w,
                                                    const float* __restrict__ pre_b,
                                                    const float* __restrict__ mix_w,
                                                    const float* __restrict__ mix_b,
                                                    float* __restrict__ alpha) {
    __shared__ float qg_s[Cn * Tn];          // [c][t]
    __shared__ float h_s[Cn * (Tn + 2)];     // [c][t+2], cols 0..1 causal zero pad
    __shared__ float mw_s[Mn * Cn * 3];
    __shared__ float l_s[Mn * Tn];
    int b = blockIdx.x;
    int tid = threadIdx.x;
    for (int i = tid; i < Cn * Tn; i += 512) qg_s[i] = qg[b * Cn * Tn + i];
    for (int i = tid; i < Mn * Cn * 3; i += 512) mw_s[i] = mix_w[i];
    __syncthreads();
    // h[o,t] = gelu(pre_w[o,:]·qg[:,t] + pre_b[o]); thread = (o, quarter-of-t)
    {
        int o = tid >> 2;
        int t0 = (tid & 3) * 8;
        float bias = pre_b[o];
        float acc[8];
#pragma unroll
        for (int j = 0; j < 8; ++j) acc[j] = 0.f;
        const float* wrow = pre_w + o * Cn;
#pragma unroll 2
        for (int cb = 0; cb < Cn; cb += 8) {
            float wv[8];
#pragma unroll
            for (int j = 0; j < 8; ++j) wv[j] = wrow[cb + j];   // 8 loads in flight
#pragma unroll
            for (int j = 0; j < 8; ++j)
#pragma unroll
                for (int i = 0; i < 8; ++i)
                    acc[i] += wv[j] * qg_s[(cb + j) * Tn + t0 + i];
        }
        if ((tid & 3) == 0) { h_s[o * (Tn + 2) + 0] = 0.f; h_s[o * (Tn + 2) + 1] = 0.f; }
#pragma unroll
        for (int j = 0; j < 8; ++j) {
            float x = acc[j] + bias;
            h_s[o * (Tn + 2) + 2 + t0 + j] = 0.5f * x * (1.0f + erff(x * 0.70710678118654752f));
        }
    }
    __syncthreads();
    // causal conv1d C->M over time (k=3, left pad 2), from LDS
    if (tid < Mn * Tn) {
        int m = tid / Tn, t = tid % Tn;
        float acc = mix_b[m];
#pragma unroll 8
        for (int c = 0; c < Cn; ++c) {
            const float* mw = mw_s + (m * Cn + c) * 3;
            const float* hp = h_s + c * (Tn + 2) + t;  // h[t-2+j] lives at col t+j
            acc += mw[0] * hp[0] + mw[1] * hp[1] + mw[2] * hp[2];
        }
        l_s[m * Tn + t] = acc;
    }
    __syncthreads();
    if (tid < Tn) {
        int t = tid;
        float l0 = l_s[t], l1 = l_s[Tn + t], l2 = l_s[2 * Tn + t];
        float mx = fmaxf(l0, fmaxf(l1, l2));
        float e0 = expf(l0 - mx), e1 = expf(l1 - mx), e2 = expf(l2 - mx);
        float inv = 1.0f / (e0 + e1 + e2);
        alpha[(b * Mn + 0) * Tn + t] = e0 * inv;
        alpha[(b * Mn + 1) * Tn + t] = e1 * inv;
        alpha[(b * Mn + 2) * Tn + t] = e2 * inv;
    }
}

// ---------------- Kernel C: dwconv3d with pre-mixed weights ----------------
// grid: 2*B*C*(T/TTile) blocks of 384; branch (k vs v) in top bid bit.
// LDS layout per plane: 26 rows x 32 floats. Row rs holds input row h_in = rs-1
// (rs=0 and rs=25 are zero pad rows). Within a row, 16B chunk jl (logical) is
// stored at jphys = jl ^ (rs & 7)  -> conflict-free ds_read_b128/ds_write_b128
// for any 8 consecutive-h lanes (each 8-lane service phase covers 32 banks).
// Logical chunk 0 = left-pad zeros, chunks 1..6 = data w=0..23 (float f holds
// w = f-4), chunk 7 = right-pad zeros.
// LDS 34.1 KiB -> 4 blocks/CU (24/32 waves).
__global__ __launch_bounds__(384, 6) void conv_kernel(const float* __restrict__ kin,
                                                      const float* __restrict__ vin,
                                                      const float* __restrict__ Wk,
                                                      const float* __restrict__ Wv,
                                                      const float* __restrict__ alpha,
                                                      float* __restrict__ out) {
    __shared__ float s[PL * PSf];         // 10 planes x 26x32 floats = 33,280 B
    __shared__ float sw[TTile * 27];      // per-t mixed weights

    int bid = blockIdx.x;
    int tt = bid & 3;
    int c  = (bid >> 2) & 127;
    int b  = (bid >> 9) & 3;
    int br = bid >> 11;                   // 0 = k branch, 1 = v branch
    int t0 = tt * TTile;
    int tid = threadIdx.x;
    const size_t plane_base = (size_t)(b * Cn + c) * Tn;
    const float* __restrict__ src = br ? vin : kin;
    const float* __restrict__ Wb  = br ? Wv : Wk;

    // 1) single fill pass: predicated global float4 loads, unconditional
    //    ds_write_b128 (pads/halo written as zeros -> no separate memset pass).
    //    slot = (plane p, storage row rs, phys chunk jp); logical chunk
    //    jl = jp ^ (rs&7); data exists for jl in 1..6, rs in 1..24, tp >= 0.
    for (int idx = tid; idx < PL * PRows * 8; idx += 384) {   // 2080 slots
        int p    = idx / (PRows * 8);
        int rem2 = idx - p * (PRows * 8);
        int rs   = rem2 >> 3;
        int jp   = rem2 & 7;
        int jl   = jp ^ (rs & 7);
        int tp   = t0 - 2 + p;
        float4 val = make_float4(0.f, 0.f, 0.f, 0.f);
        if (tp >= 0 && (unsigned)(rs - 1) < 24u && (unsigned)(jl - 1) < 6u)
            val = *(const float4*)(src + (plane_base + tp) * HWn + (rs - 1) * 24 + (jl - 1) * 4);
        *(float4*)(s + p * PSf + rs * RSf + jp * 4) = val;
    }
    // 2) mix weights: W_eff[t] = sum_m alpha[b,m,t0+t] * Wb[m,c,:]
    if (tid < TTile * 27) {
        int tl = tid / 27;
        int widx = tid - tl * 27;
        float a0 = alpha[(b * Mn + 0) * Tn + t0 + tl];
        float a1 = alpha[(b * Mn + 1) * Tn + t0 + tl];
        float a2 = alpha[(b * Mn + 2) * Tn + t0 + tl];
        sw[tid] = a0 * Wb[(0 * Cn + c) * 27 + widx]
                + a1 * Wb[(1 * Cn + c) * 27 + widx]
                + a2 * Wb[(2 * Cn + c) * 27 + widx];
    }
    __syncthreads();

    // 3) compute. s-major lane mapping: tid = tl*48 + sH*24 + h, so each 8-lane
    //    LDS phase has uniform (tl,sH) and h = 0..7 (mod 8) -> conflict-free.
    //    Thread computes outputs (t0+tl, h, w0..w0+11), w0 = 12*sH.
    int tl  = tid / 48;
    int rem = tid - tl * 48;
    int sH  = rem / 24;                   // w-half
    int h   = rem - sH * 24;
    int w0  = sH * 12;
    int cBase = 3 * sH;                   // first logical chunk of this half's window
    const float* wrow = sw + tl * 27;
    float acc[12];
#pragma unroll
    for (int j = 0; j < 12; ++j) acc[j] = 0.f;
#pragma unroll
    for (int dt = 0; dt < 3; ++dt) {
        const float* pp = s + (tl + dt) * PSf;
        float wd[9];
#pragma unroll
        for (int j = 0; j < 9; ++j) wd[j] = wrow[dt * 9 + j];
#pragma unroll
        for (int dh = 0; dh < 3; ++dh) {
            int rs = h + dh;              // storage row for input row h-1+dh
            const float* rp = pp + rs * RSf;
            int key = rs & 7;
            float bf[20];                 // logical floats [w0 .. w0+19]
#pragma unroll
            for (int cc = 0; cc < 5; ++cc) {
                int jp = (cBase + cc) ^ key;
                float4 t4 = *(const float4*)(rp + jp * 4);
                bf[cc * 4 + 0] = t4.x; bf[cc * 4 + 1] = t4.y;
                bf[cc * 4 + 2] = t4.z; bf[cc * 4 + 3] = t4.w;
            }
            // input w' = (w0+j) - 1 + dw lives at bf[j + dw + 3]
#pragma unroll
            for (int dw = 0; dw < 3; ++dw) {
                float wc = wd[dh * 3 + dw];
#pragma unroll
                for (int j = 0; j < 12; ++j) acc[j] += bf[j + dw + 3] * wc;
            }
        }
    }
    size_t obase = (plane_base + t0 + tl) * HWn + h * Wn + w0;   // float4-aligned
    float* op = out + (br ? (size_t)Bn * Cn * Tn * HWn : 0) + obase;
#pragma unroll
    for (int j = 0; j < 3; ++j)
        ((float4*)op)[j] = make_float4(acc[4*j], acc[4*j+1], acc[4*j+2], acc[4*j+3]);
}

extern "C" void kernel_launch(void* const* d_in, const int* in_sizes, int n_in,
                              void* d_out, int out_size, void* d_ws, size_t ws_size,
                              hipStream_t stream) {
    const float* q     = (const float*)d_in[0];
    const float* k     = (const float*)d_in[1];
    const float* v     = (const float*)d_in[2];
    const float* Wk    = (const float*)d_in[3];
    const float* Wv    = (const float*)d_in[4];
    const float* pre_w = (const float*)d_in[5];
    const float* pre_b = (const float*)d_in[6];
    const float* mix_w = (const float*)d_in[7];
    const float* mix_b = (const float*)d_in[8];
    float* out = (float*)d_out;

    float* qg    = (float*)d_ws;            // B*C*T = 16384 floats
    float* alpha = qg + Bn * Cn * Tn;       // B*M*T = 384 floats

    hipLaunchKernelGGL(pool_kernel, dim3(Bn * Cn * Tn / 4), dim3(256), 0, stream, q, qg);
    hipLaunchKernelGGL(alpha_kernel, dim3(Bn), dim3(512), 0, stream,
                       qg, pre_w, pre_b, mix_w, mix_b, alpha);
    hipLaunchKernelGGL(conv_kernel, dim3(2 * Bn * Cn * (Tn / TTile)), dim3(384), 0, stream,
                       k, v, Wk, Wv, alpha, out);
}

// Round 2
// 203.467 us; speedup vs baseline: 1.3419x; 1.3419x over previous
//
#include <hip/hip_runtime.h>
#include <math.h>

// Problem dims (fixed by setup_inputs)
namespace {
constexpr int Bn = 4, Cn = 128, Tn = 32, Hn = 24, Wn = 24, Mn = 3;
constexpr int HWn = Hn * Wn;      // 576
constexpr int TTile = 8;          // time tile per conv block
constexpr int PL = TTile + 2;     // input planes per tile (causal halo 2)
constexpr int RS = 28;            // LDS row stride (col0 = left pad, cols 1-24 = data, 25-27 = right pad)
constexpr int PS = 26 * RS;       // plane stride in LDS floats (728)
}

// ---------------- Kernel A: spatial mean pool q -> qg[B*C*T] ----------------
// 4 planes per 256-thread block (1 wave per plane), float4 loads.
__global__ __launch_bounds__(256) void pool_kernel(const float* __restrict__ q,
                                                   float* __restrict__ qg) {
    int wave = threadIdx.x >> 6;
    int lane = threadIdx.x & 63;
    int plane = blockIdx.x * 4 + wave;
    const float4* p = (const float4*)(q + (size_t)plane * HWn);  // 144 float4
    float4 a = p[lane];
    float4 b = p[lane + 64];
    float s = (a.x + a.y) + (a.z + a.w) + (b.x + b.y) + (b.z + b.w);
    if (lane < 16) {
        float4 c = p[128 + lane];
        s += (c.x + c.y) + (c.z + c.w);
    }
#pragma unroll
    for (int off = 32; off > 0; off >>= 1) s += __shfl_down(s, off);
    if (lane == 0) qg[plane] = s * (1.0f / 576.0f);
}

// ---------------- Kernel B: alpha[B*M*T] from qg ----------------
__global__ __launch_bounds__(512) void alpha_kernel(const float* __restrict__ qg,
                                                    const float* __restrict__ pre_w,
                                                    const float* __restrict__ pre_b,
                                                    const float* __restrict__ mix_w,
                                                    const float* __restrict__ mix_b,
                                                    float* __restrict__ alpha) {
    __shared__ float qg_s[Cn * Tn];          // [c][t]
    __shared__ float h_s[Cn * (Tn + 2)];     // [c][t+2], cols 0..1 causal zero pad
    __shared__ float mw_s[Mn * Cn * 3];
    __shared__ float l_s[Mn * Tn];
    int b = blockIdx.x;
    int tid = threadIdx.x;
    for (int i = tid; i < Cn * Tn; i += 512) qg_s[i] = qg[b * Cn * Tn + i];
    for (int i = tid; i < Mn * Cn * 3; i += 512) mw_s[i] = mix_w[i];
    __syncthreads();
    // h[o,t] = gelu(pre_w[o,:]·qg[:,t] + pre_b[o]); thread = (o, quarter-of-t)
    {
        int o = tid >> 2;
        int t0 = (tid & 3) * 8;
        float bias = pre_b[o];
        float acc[8];
#pragma unroll
        for (int j = 0; j < 8; ++j) acc[j] = 0.f;
        const float* wrow = pre_w + o * Cn;
#pragma unroll 2
        for (int cb = 0; cb < Cn; cb += 8) {
            float wv[8];
#pragma unroll
            for (int j = 0; j < 8; ++j) wv[j] = wrow[cb + j];   // 8 loads in flight
#pragma unroll
            for (int j = 0; j < 8; ++j)
#pragma unroll
                for (int i = 0; i < 8; ++i)
                    acc[i] += wv[j] * qg_s[(cb + j) * Tn + t0 + i];
        }
        if ((tid & 3) == 0) { h_s[o * (Tn + 2) + 0] = 0.f; h_s[o * (Tn + 2) + 1] = 0.f; }
#pragma unroll
        for (int j = 0; j < 8; ++j) {
            float x = acc[j] + bias;
            h_s[o * (Tn + 2) + 2 + t0 + j] = 0.5f * x * (1.0f + erff(x * 0.70710678118654752f));
        }
    }
    __syncthreads();
    // causal conv1d C->M over time (k=3, left pad 2), from LDS
    if (tid < Mn * Tn) {
        int m = tid / Tn, t = tid % Tn;
        float acc = mix_b[m];
#pragma unroll 8
        for (int c = 0; c < Cn; ++c) {
            const float* mw = mw_s + (m * Cn + c) * 3;
            const float* hp = h_s + c * (Tn + 2) + t;  // h[t-2+j] lives at col t+j
            acc += mw[0] * hp[0] + mw[1] * hp[1] + mw[2] * hp[2];
        }
        l_s[m * Tn + t] = acc;
    }
    __syncthreads();
    if (tid < Tn) {
        int t = tid;
        float l0 = l_s[t], l1 = l_s[Tn + t], l2 = l_s[2 * Tn + t];
        float mx = fmaxf(l0, fmaxf(l1, l2));
        float e0 = expf(l0 - mx), e1 = expf(l1 - mx), e2 = expf(l2 - mx);
        float inv = 1.0f / (e0 + e1 + e2);
        alpha[(b * Mn + 0) * Tn + t] = e0 * inv;
        alpha[(b * Mn + 1) * Tn + t] = e1 * inv;
        alpha[(b * Mn + 2) * Tn + t] = e2 * inv;
    }
}

// ---------------- Kernel C: dwconv3d with pre-mixed weights ----------------
// grid: 2*B*C*(T/TTile) blocks of 384; branch (k vs v) in top bid bit.
// LDS layout identical to the verified round-0 kernel: 26 rows x 28 floats per
// plane; col 0 = left pad, cols 1-24 = w 0-23, cols 25-27 = right pad. Rows
// rs=0 (h=-1) and rs=25 (h=24) are zero. Filled in a SINGLE pass: one thread
// per (plane,row), 6 aligned global float4 loads, 7 aligned ds_write_b128 of
// register-shifted chunks (pads composed in-register). One barrier total.
// LDS ~30 KiB -> 5 blocks/CU (30/32 waves).
__global__ __launch_bounds__(384) void conv_kernel(const float* __restrict__ kin,
                                                   const float* __restrict__ vin,
                                                   const float* __restrict__ Wk,
                                                   const float* __restrict__ Wv,
                                                   const float* __restrict__ alpha,
                                                   float* __restrict__ out) {
    __shared__ float s[PL * PS];          // 10 planes, 26x28 floats = 29,120 B
    __shared__ float sw[TTile * 27];      // per-t mixed weights

    int bid = blockIdx.x;
    int tt = bid & 3;
    int c  = (bid >> 2) & 127;
    int b  = (bid >> 9) & 3;
    int br = bid >> 11;                   // 0 = k branch, 1 = v branch
    int t0 = tt * TTile;
    int tid = threadIdx.x;
    const size_t plane_base = (size_t)(b * Cn + c) * Tn;
    const float* __restrict__ src = br ? vin : kin;
    const float* __restrict__ Wb  = br ? Wv : Wk;

    // 1) single-pass fill: thread = (plane p, storage row rs); rs holds input
    //    row h = rs-1. Valid data rows load 24 floats (6x float4) and write 7
    //    aligned b128 chunks with the left/right pads composed in registers.
    //    Invalid rows (h pad rows, causal tp<0 planes) write zeros.
    if (tid < PL * 26) {                  // 260 fill tasks
        int p  = tid / 26;
        int rs = tid - p * 26;
        int tp = t0 - 2 + p;
        float4 g0, g1, g2, g3, g4, g5;
        bool valid = (tp >= 0) && ((unsigned)(rs - 1) < 24u);
        if (valid) {
            const float4* grow = (const float4*)(src + (plane_base + tp) * HWn + (rs - 1) * 24);
            g0 = grow[0]; g1 = grow[1]; g2 = grow[2];
            g3 = grow[3]; g4 = grow[4]; g5 = grow[5];
        } else {
            float4 z = make_float4(0.f, 0.f, 0.f, 0.f);
            g0 = z; g1 = z; g2 = z; g3 = z; g4 = z; g5 = z;
        }
        float4* dst = (float4*)(s + p * PS + rs * RS);
        dst[0] = make_float4(0.f,  g0.x, g0.y, g0.z);   // cols 0-3   (pad, w0-2)
        dst[1] = make_float4(g0.w, g1.x, g1.y, g1.z);   // cols 4-7   (w3-6)
        dst[2] = make_float4(g1.w, g2.x, g2.y, g2.z);   // cols 8-11  (w7-10)
        dst[3] = make_float4(g2.w, g3.x, g3.y, g3.z);   // cols 12-15 (w11-14)
        dst[4] = make_float4(g3.w, g4.x, g4.y, g4.z);   // cols 16-19 (w15-18)
        dst[5] = make_float4(g4.w, g5.x, g5.y, g5.z);   // cols 20-23 (w19-22)
        dst[6] = make_float4(g5.w, 0.f,  0.f,  0.f);    // cols 24-27 (w23, pads)
    }
    // 2) mix weights: W_eff[t] = sum_m alpha[b,m,t0+t] * Wb[m,c,:]
    if (tid < TTile * 27) {
        int tl = tid / 27;
        int widx = tid - tl * 27;
        float a0 = alpha[(b * Mn + 0) * Tn + t0 + tl];
        float a1 = alpha[(b * Mn + 1) * Tn + t0 + tl];
        float a2 = alpha[(b * Mn + 2) * Tn + t0 + tl];
        sw[tid] = a0 * Wb[(0 * Cn + c) * 27 + widx]
                + a1 * Wb[(1 * Cn + c) * 27 + widx]
                + a2 * Wb[(2 * Cn + c) * 27 + widx];
    }
    __syncthreads();

    // 3) compute: thread = (t_local, h, half-row of 12 outputs) — identical to
    //    the verified round-0 mapping (store coalescing pattern preserved).
    int tl = tid / 48;
    int rem = tid - tl * 48;
    int h = rem >> 1;
    int w0 = (rem & 1) * 12;
    const float* wp = sw + tl * 27;
    float acc[12];
#pragma unroll
    for (int j = 0; j < 12; ++j) acc[j] = 0.f;
#pragma unroll
    for (int dt = 0; dt < 3; ++dt) {
#pragma unroll
        for (int dh = 0; dh < 3; ++dh) {
            const float* rp = s + (tl + dt) * PS + (h + dh) * RS + w0;  // 16B-aligned
            float bf[14];
#pragma unroll
            for (int j = 0; j < 14; ++j) bf[j] = rp[j];
#pragma unroll
            for (int dw = 0; dw < 3; ++dw) {
                float wc = wp[dt * 9 + dh * 3 + dw];
#pragma unroll
                for (int j = 0; j < 12; ++j) acc[j] += bf[j + dw] * wc;
            }
        }
    }
    size_t obase = (plane_base + t0 + tl) * HWn + h * Wn + w0;   // float4-aligned
    float* op = out + (br ? (size_t)Bn * Cn * Tn * HWn : 0) + obase;
#pragma unroll
    for (int j = 0; j < 3; ++j)
        ((float4*)op)[j] = make_float4(acc[4*j], acc[4*j+1], acc[4*j+2], acc[4*j+3]);
}

extern "C" void kernel_launch(void* const* d_in, const int* in_sizes, int n_in,
                              void* d_out, int out_size, void* d_ws, size_t ws_size,
                              hipStream_t stream) {
    const float* q     = (const float*)d_in[0];
    const float* k     = (const float*)d_in[1];
    const float* v     = (const float*)d_in[2];
    const float* Wk    = (const float*)d_in[3];
    const float* Wv    = (const float*)d_in[4];
    const float* pre_w = (const float*)d_in[5];
    const float* pre_b = (const float*)d_in[6];
    const float* mix_w = (const float*)d_in[7];
    const float* mix_b = (const float*)d_in[8];
    float* out = (float*)d_out;

    float* qg    = (float*)d_ws;            // B*C*T = 16384 floats
    float* alpha = qg + Bn * Cn * Tn;       // B*M*T = 384 floats

    hipLaunchKernelGGL(pool_kernel, dim3(Bn * Cn * Tn / 4), dim3(256), 0, stream, q, qg);
    hipLaunchKernelGGL(alpha_kernel, dim3(Bn), dim3(512), 0, stream,
                       qg, pre_w, pre_b, mix_w, mix_b, alpha);
    hipLaunchKernelGGL(conv_kernel, dim3(2 * Bn * Cn * (Tn / TTile)), dim3(384), 0, stream,
                       k, v, Wk, Wv, alpha, out);
}